// Round 5
// baseline (122.577 us; speedup 1.0000x reference)
//
#include <hip/hip_runtime.h>
#include <stdint.h>

#define NBATCH 2
#define LL 4096
#define CC 256
#define KEXP 0.09016844f   // (1/16) * log2(e)  : exp(acc/16) = exp2(acc*KEXP)
#define KEXP2 0.18033688f  // (2/16) * log2(e)
#define IMIN (-2147483647 - 1)

typedef long i64f;
typedef float f32x4 __attribute__((ext_vector_type(4)));

#if defined(__has_builtin) && __has_builtin(__builtin_amdgcn_exp2f)
#define EXP2F(x) __builtin_amdgcn_exp2f(x)
#else
#define EXP2F(x) exp2f(x)
#endif

// async 16B global -> LDS (dest = wave-uniform base + lane*16)
#define GLDS16(g, l) __builtin_amdgcn_global_load_lds(                      \
    (const __attribute__((address_space(1))) uint32_t*)(g),                 \
    (__attribute__((address_space(3))) uint32_t*)(l), 16, 0, 0)

// ---------------- cast fp32 -> fp8 e4m3 (OCP, HW packer) + accum init -------
__global__ __launch_bounds__(256) void cast_fp8(
    const float* __restrict__ a, const float* __restrict__ b,
    uint32_t* __restrict__ oa, uint32_t* __restrict__ ob,
    float* __restrict__ rowSum, float* __restrict__ colSum,
    int* __restrict__ rowPart, int* __restrict__ colPart){
  int idx = blockIdx.x * 256 + threadIdx.x;   // one uint32 = 4 fp8 per thread
  if (idx < NBATCH*LL){
    rowSum[idx] = 0.f; colSum[idx] = 0.f;
    rowPart[idx] = IMIN; colPart[idx] = IMIN;
  }
  float4 va = ((const float4*)a)[idx];
  float4 vb = ((const float4*)b)[idx];
  int ra = __builtin_amdgcn_cvt_pk_fp8_f32(va.x, va.y, 0, false);
  ra = __builtin_amdgcn_cvt_pk_fp8_f32(va.z, va.w, ra, true);
  int rb = __builtin_amdgcn_cvt_pk_fp8_f32(vb.x, vb.y, 0, false);
  rb = __builtin_amdgcn_cvt_pk_fp8_f32(vb.z, vb.w, rb, true);
  oa[idx] = (uint32_t)ra;
  ob[idx] = (uint32_t)rb;
}

// ---------------- single conf pass: fp8 128x128, 2 K-chunks ----------------
// R14: linear 128B LDS rows + XOR swizzle, glds width=16 chunk-0 staging.
// R15: counted vmcnt(16) + raw s_barrier before compute-0 (waits only the 8
// glds, leaves the 16 chunk-1 prefetch loads in flight across compute-0);
// s_setprio(1) around MFMA clusters (blocks independently phased on a CU).
// C/D layout [m89]: l = lq*64+r*16+quad*4+rr, s = sq*64+j*16+lr
__global__ __launch_bounds__(256, 4) void conf_pass(
    const uint8_t* __restrict__ f0q, const uint8_t* __restrict__ f1q,
    float* __restrict__ rowSum, float* __restrict__ colSum,
    int* __restrict__ rowPart, int* __restrict__ colPart){
  __shared__ __align__(16) uint8_t Alds[128*128];
  __shared__ __align__(16) uint8_t Blds[128*128];
  float* rowS = (float*)Alds;            // [2][128] overlay (valid after MFMA)
  float* colS = (float*)(Alds + 1024);   // [2][128]
  int*   rb   = (int*)  (Alds + 2048);   // [2][128]
  int*   cb   = (int*)  (Alds + 3072);   // [2][128]
  // XCD-chunked swizzle: 2048 blocks, 8 XCDs, 256 contiguous tiles per XCD.
  int bl = (blockIdx.z*32 + blockIdx.y)*32 + blockIdx.x;
  int nb = (bl & 7)*256 + (bl >> 3);
  int st = nb & 31, lt = (nb >> 5) & 31, n = nb >> 10;
  int t = threadIdx.x;
  const int wv = t >> 6, lane = t & 63, lr = lane & 15, quad = lane >> 4;
  const int lq = wv >> 1, sq = wv & 1;
  const int swzr = (lr & 7) << 4;        // frag-read XOR (row&7 == lr&7)
  const uint8_t* A = f0q + (size_t)n*LL*CC + (size_t)(lt*128)*CC;
  const uint8_t* B = f1q + (size_t)n*LL*CC + (size_t)(st*128)*CC;
  f32x4 acc[4][4];
  #pragma unroll
  for (int r = 0; r < 4; r++)
    #pragma unroll
    for (int j = 0; j < 4; j++) acc[r][j] = (f32x4){0.f,0.f,0.f,0.f};

  auto compute = [&](){
    __builtin_amdgcn_s_setprio(1);
    #pragma unroll
    for (int kk = 0; kk < 4; kk++){
      int off = (kk*32 + quad*8) ^ swzr;
      i64f a[4], bf[4];
      #pragma unroll
      for (int r = 0; r < 4; r++)
        a[r] = *(const i64f*)(Alds + (lq*64 + r*16 + lr)*128 + off);
      #pragma unroll
      for (int j = 0; j < 4; j++)
        bf[j] = *(const i64f*)(Blds + (sq*64 + j*16 + lr)*128 + off);
      #pragma unroll
      for (int r = 0; r < 4; r++)
        #pragma unroll
        for (int j = 0; j < 4; j++)
          acc[r][j] = __builtin_amdgcn_mfma_f32_16x16x32_fp8_fp8(a[r], bf[j], acc[r][j], 0, 0, 0);
    }
    __builtin_amdgcn_s_setprio(0);
  };

  // ---- chunk 0: async global_load_lds, 16B/lane, pre-swizzled source ----
  {
    int rsub = lane >> 3, csub = lane & 7;
    int srcOff = ((csub ^ rsub) << 4);           // row&7 == rsub here
    #pragma unroll
    for (int m = 0; m < 4; m++){
      int row = m*32 + wv*8 + rsub;
      GLDS16(A + (size_t)row*CC + srcOff, Alds + m*4096 + wv*1024);
      GLDS16(B + (size_t)row*CC + srcOff, Blds + m*4096 + wv*1024);
    }
  }
  __builtin_amdgcn_sched_barrier(0);   // pin: 8 glds issue BEFORE prefetch loads
  // ---- chunk-1 prefetch into registers (stays in flight across compute 0) --
  uint2 pa[8], pb[8];
  #pragma unroll
  for (int m = 0; m < 8; m++){
    int f = m*256 + t, row = f >> 4, kg = f & 15;
    int so = (kg*8) ^ ((row & 7) << 4);
    pa[m] = *(const uint2*)(A + (size_t)row*CC + 128 + so);
    pb[m] = *(const uint2*)(B + (size_t)row*CC + 128 + so);
  }
  // wait ONLY the 8 oldest vmem ops (the glds) -> prefetch stays outstanding
  asm volatile("s_waitcnt vmcnt(16)" ::: "memory");
  __builtin_amdgcn_s_barrier();
  __builtin_amdgcn_sched_barrier(0);
  compute();          // chunk 0 (chunk-1 prefetch loads still in flight)
  __syncthreads();
  #pragma unroll
  for (int m = 0; m < 8; m++){
    int f = m*256 + t, row = f >> 4, kg = f & 15;
    *(uint2*)(Alds + row*128 + kg*8) = pa[m];
    *(uint2*)(Blds + row*128 + kg*8) = pb[m];
  }
  __syncthreads();
  compute();          // chunk 1

  // ---- epilogue: exp-sums + packed argmax keys (registers + shuffles) ----
  const int sbase = st*128 + sq*64 + lr;        // + j*16
  const int lbase = lt*128 + lq*64 + quad*4;    // + r*16 + rr
  float rsum[4][4], csum[4] = {0.f,0.f,0.f,0.f};
  int rkey[4][4], ckey[4] = {IMIN,IMIN,IMIN,IMIN};
  #pragma unroll
  for (int r = 0; r < 4; r++)
    #pragma unroll
    for (int rr = 0; rr < 4; rr++){ rsum[r][rr] = 0.f; rkey[r][rr] = IMIN; }
  #pragma unroll
  for (int r = 0; r < 4; r++)
    #pragma unroll
    for (int j = 0; j < 4; j++)
      #pragma unroll
      for (int rr = 0; rr < 4; rr++){
        float a = acc[r][j][rr];
        float e = EXP2F(a * KEXP);
        rsum[r][rr] += e;
        csum[j] += e;
        int iqs = ((int)(a * 2048.f)) << 12;
        rkey[r][rr] = max(rkey[r][rr], iqs + (sbase + j*16));
        ckey[j]     = max(ckey[j],     iqs + (lbase + r*16 + rr));
      }
  #pragma unroll
  for (int msk = 1; msk <= 8; msk <<= 1)
    #pragma unroll
    for (int r = 0; r < 4; r++)
      #pragma unroll
      for (int rr = 0; rr < 4; rr++){
        rsum[r][rr] += __shfl_xor(rsum[r][rr], msk);
        rkey[r][rr] = max(rkey[r][rr], __shfl_xor(rkey[r][rr], msk));
      }
  #pragma unroll
  for (int msk = 16; msk <= 32; msk <<= 1)
    #pragma unroll
    for (int j = 0; j < 4; j++){
      csum[j] += __shfl_xor(csum[j], msk);
      ckey[j] = max(ckey[j], __shfl_xor(ckey[j], msk));
    }
  __syncthreads();   // all waves done reading tile LDS -> overlay is safe
  if (lr == 0){
    #pragma unroll
    for (int r = 0; r < 4; r++)
      #pragma unroll
      for (int rr = 0; rr < 4; rr++){
        int row = lq*64 + r*16 + quad*4 + rr;
        rowS[sq*128 + row] = rsum[r][rr];   // single writer per slot
        rb[sq*128 + row]   = rkey[r][rr];
      }
  }
  if (quad == 0){
    #pragma unroll
    for (int j = 0; j < 4; j++){
      int col = sq*64 + j*16 + lr;
      colS[lq*128 + col] = csum[j];
      cb[lq*128 + col]   = ckey[j];
    }
  }
  __syncthreads();
  if (t < 128){
    unsafeAtomicAdd(&rowSum[(size_t)n*LL + lt*128 + t], rowS[t] + rowS[128 + t]);
    unsafeAtomicAdd(&colSum[(size_t)n*LL + st*128 + t], colS[t] + colS[128 + t]);
    atomicMax(&rowPart[(size_t)n*LL + lt*128 + t], max(rb[t], rb[128 + t]));
    atomicMax(&colPart[(size_t)n*LL + st*128 + t], max(cb[t], cb[128 + t]));
  }
}

// ---------------- on-the-fly fea for the rare mask hit ----------------
__device__ float fea_fly(const float* __restrict__ featn, int srow, int t){
  __shared__ float sred[9][4];
  __shared__ float ssem[9];
  int lane = t & 63, wv = t >> 6;
  int h = srow >> 6, xx = srow & 63;
  float fv = featn[(size_t)srow * CC + t];
  float uv[9];
  #pragma unroll
  for (int w = 0; w < 9; w++){
    int dy = w/3 - 1, dx = w%3 - 1;
    int y = h + dy, x = xx + dx;
    uv[w] = (y >= 0 && y < 64 && x >= 0 && x < 64) ? featn[(size_t)t * 4096 + y*64 + x] : 0.f;
  }
  __syncthreads();
  #pragma unroll
  for (int w = 0; w < 9; w++){
    float pvv = fv * uv[w];
    #pragma unroll
    for (int msk = 1; msk <= 32; msk <<= 1) pvv += __shfl_xor(pvv, msk);
    if (lane == 0) sred[w][wv] = pvv;
  }
  __syncthreads();
  if (t < 9) ssem[t] = (sred[t][0] + sred[t][1] + sred[t][2] + sred[t][3]) * (1.f/256.f);
  __syncthreads();
  float acc = 0.f;
  #pragma unroll
  for (int w = 0; w < 9; w++) acc += uv[w] * ssem[w];
  __syncthreads();
  return acc;
}

__device__ __forceinline__ float pool_window(const float* f, const float* s, int t){
  if (t < 160){
    int a = (t*8)/5, e = (t*8+12)/5;
    float sum = 0.f;
    for (int i = a; i < e; i++) sum += f[i];
    return sum / (float)(e - a);
  } else {
    int tt = t - 160;
    int a = (tt*8)/3, e = (tt*8+10)/3;
    float sum = 0.f;
    for (int i = a; i < e; i++) sum += s[i];
    return sum / (float)(e - a);
  }
}

// ---------------- fused tail: mutual-NN check + pool + LN -------------------
// R15: 4 rows per block (grid 2048): block preamble + lnw/lnb amortized 4x,
// the 2-deep dependent uniform-scalar gather batched across rows (2 latency
// rounds total instead of 8).
__global__ __launch_bounds__(256) void tail(
    const float* __restrict__ feat0, const float* __restrict__ feat1,
    const float* __restrict__ rowSum, const float* __restrict__ colSum,
    const int* __restrict__ rowPart, const int* __restrict__ colPart,
    const float* __restrict__ lnw, const float* __restrict__ lnb,
    float* __restrict__ out){
  int l0 = blockIdx.x * 4, n = blockIdx.y, t = threadIdx.x;
  int lane = t & 63, wv = t >> 6;
  size_t base = (size_t)n * LL;
  float w = lnw[t], bsh = lnb[t];
  // ---- level-1 loads for all 4 rows (independent; issue together) ----
  float fv0[4], fv1[4], Rl[4], Cl[4];
  int rowK[4], colK[4];
  #pragma unroll
  for (int i = 0; i < 4; i++){
    fv0[i]  = feat0[(base + l0 + i)*CC + t];
    fv1[i]  = feat1[(base + l0 + i)*CC + t];
    rowK[i] = rowPart[base + l0 + i];
    colK[i] = colPart[base + l0 + i];
    Rl[i]   = rowSum[base + l0 + i];
    Cl[i]   = colSum[base + l0 + i];
  }
  // ---- level-2 gathers (depend only on level-1; issue together) ----
  int ssr[4], ssc[4], ck2[4], rk2[4];
  float Cssr[4], Rssc[4];
  #pragma unroll
  for (int i = 0; i < 4; i++){
    ssr[i] = rowK[i] & 4095;
    ssc[i] = colK[i] & 4095;
    Cssr[i] = colSum[base + ssr[i]];
    Rssc[i] = rowSum[base + ssc[i]];
    ck2[i]  = colPart[base + ssr[i]];
    rk2[i]  = rowPart[base + ssc[i]];
  }
  __shared__ float f0r[CC], f1r[CC], s0r[CC], s1r[CC];
  __shared__ float redA[2][4], redB[2][4];
  for (int i = 0; i < 4; i++){
    int l = l0 + i;
    float v0 = 0.f, v1 = 0.f;
    {
      float araw = (float)(rowK[i] >> 12) * (1.f/2048.f);
      float val = exp2f(araw * KEXP2) / (Rl[i] * Cssr[i]);   // conf'(l,ssr)
      if (val > 0.2f && (ck2[i] & 4095) == l)                // uniform branch
        v0 = fea_fly(feat1 + (size_t)n*LL*CC, ssr[i], t) * (1.f/4096.f);
    }
    {
      float araw = (float)(colK[i] >> 12) * (1.f/2048.f);
      float val = exp2f(araw * KEXP2) / (Cl[i] * Rssc[i]);   // conf'(ssc,l)
      if (val > 0.2f && (rk2[i] & 4095) == l)                // uniform branch
        v1 = fea_fly(feat0 + (size_t)n*LL*CC, ssc[i], t) * (1.f/4096.f);
    }
    // ---- pool + LN ----
    f0r[t] = fv0[i];
    f1r[t] = fv1[i];
    s0r[t] = v0;
    s1r[t] = v1;
    __syncthreads();
    float pA = pool_window(f0r, s0r, t);
    float pB = pool_window(f1r, s1r, t);
    float smA = pA, sqA = pA*pA, smB = pB, sqB = pB*pB;
    #pragma unroll
    for (int msk = 1; msk <= 32; msk <<= 1){
      smA += __shfl_xor(smA, msk);
      sqA += __shfl_xor(sqA, msk);
      smB += __shfl_xor(smB, msk);
      sqB += __shfl_xor(sqB, msk);
    }
    if (lane == 0){ redA[0][wv] = smA; redA[1][wv] = sqA; redB[0][wv] = smB; redB[1][wv] = sqB; }
    __syncthreads();
    float tsA = redA[0][0]+redA[0][1]+redA[0][2]+redA[0][3];
    float tqA = redA[1][0]+redA[1][1]+redA[1][2]+redA[1][3];
    float tsB = redB[0][0]+redB[0][1]+redB[0][2]+redB[0][3];
    float tqB = redB[1][0]+redB[1][1]+redB[1][2]+redB[1][3];
    float muA = tsA * (1.f/256.f), varA = tqA * (1.f/256.f) - muA*muA;
    float muB = tsB * (1.f/256.f), varB = tqB * (1.f/256.f) - muB*muB;
    out[((size_t)n*LL + l)*CC + t]       = (pA - muA) * rsqrtf(varA + 1e-5f) * w + bsh;
    out[((size_t)(2 + n)*LL + l)*CC + t] = (pB - muB) * rsqrtf(varB + 1e-5f) * w + bsh;
    __syncthreads();   // protect f0r..s1r / red* before next row's writes
  }
}

extern "C" void kernel_launch(void* const* d_in, const int* in_sizes, int n_in,
                              void* d_out, int out_size, void* d_ws, size_t ws_size,
                              hipStream_t stream){
  const float* feat0 = (const float*)d_in[0];
  const float* feat1 = (const float*)d_in[1];
  const float* lnw   = (const float*)d_in[2];
  const float* lnb   = (const float*)d_in[3];
  float* out = (float*)d_out;
  char* ws = (char*)d_ws;
  const size_t MB = 1024 * 1024;
  uint8_t* f0q = (uint8_t*)(ws + 0);        // 2 MB fp8
  uint8_t* f1q = (uint8_t*)(ws + 2*MB);     // 2 MB fp8
  float* rowSum  = (float*)(ws + 4*MB);            // [2][4096] = 32 KB
  float* colSum  = (float*)(ws + 4*MB + 32*1024);  // 32 KB
  int*   rowPart = (int*)  (ws + 4*MB + 64*1024);  // 32 KB
  int*   colPart = (int*)  (ws + 4*MB + 96*1024);  // 32 KB

  cast_fp8<<<2048, 256, 0, stream>>>(feat0, feat1, (uint32_t*)f0q, (uint32_t*)f1q,
                                     rowSum, colSum, rowPart, colPart);
  dim3 gconf(32, 32, NBATCH);
  conf_pass<<<gconf, 256, 0, stream>>>(f0q, f1q, rowSum, colSum, rowPart, colPart);
  dim3 gt(LL/4, NBATCH);
  tail<<<gt, 256, 0, stream>>>(feat0, feat1, rowSum, colSum, rowPart, colPart,
                               lnw, lnb, out);
}

// Round 6
// 117.733 us; speedup vs baseline: 1.0411x; 1.0411x over previous
//
#include <hip/hip_runtime.h>
#include <stdint.h>

#define NBATCH 2
#define LL 4096
#define CC 256
#define KEXP 0.09016844f   // (1/16) * log2(e)  : exp(acc/16) = exp2(acc*KEXP)
#define KEXP2 0.18033688f  // (2/16) * log2(e)
#define IMIN (-2147483647 - 1)

typedef long i64f;
typedef float f32x4 __attribute__((ext_vector_type(4)));

#if defined(__has_builtin) && __has_builtin(__builtin_amdgcn_exp2f)
#define EXP2F(x) __builtin_amdgcn_exp2f(x)
#else
#define EXP2F(x) exp2f(x)
#endif

// async 16B global -> LDS (dest = wave-uniform base + lane*16)
#define GLDS16(g, l) __builtin_amdgcn_global_load_lds(                      \
    (const __attribute__((address_space(1))) uint32_t*)(g),                 \
    (__attribute__((address_space(3))) uint32_t*)(l), 16, 0, 0)

// ---------------- cast fp32 -> fp8 e4m3 (OCP, HW packer) + accum init -------
__global__ __launch_bounds__(256) void cast_fp8(
    const float* __restrict__ a, const float* __restrict__ b,
    uint32_t* __restrict__ oa, uint32_t* __restrict__ ob,
    float* __restrict__ rowSum, float* __restrict__ colSum,
    int* __restrict__ rowPart, int* __restrict__ colPart){
  int idx = blockIdx.x * 256 + threadIdx.x;   // one uint32 = 4 fp8 per thread
  if (idx < NBATCH*LL){
    rowSum[idx] = 0.f; colSum[idx] = 0.f;
    rowPart[idx] = IMIN; colPart[idx] = IMIN;
  }
  float4 va = ((const float4*)a)[idx];
  float4 vb = ((const float4*)b)[idx];
  int ra = __builtin_amdgcn_cvt_pk_fp8_f32(va.x, va.y, 0, false);
  ra = __builtin_amdgcn_cvt_pk_fp8_f32(va.z, va.w, ra, true);
  int rb = __builtin_amdgcn_cvt_pk_fp8_f32(vb.x, vb.y, 0, false);
  rb = __builtin_amdgcn_cvt_pk_fp8_f32(vb.z, vb.w, rb, true);
  oa[idx] = (uint32_t)ra;
  ob[idx] = (uint32_t)rb;
}

// ---------------- single conf pass: fp8 128x128, 2 K-chunks ----------------
// R14: linear 128B LDS rows + XOR swizzle, glds width=16 chunk-0 staging.
// R15: counted vmcnt(16) + raw s_barrier; setprio around MFMA.
// R16: value-split butterfly reduction (15 shuffles per 16-value array vs 64;
// lane ends owning value bitrev4(lr)) + fully-parallel overlay writes +
// atomic phase spread over all 256 threads.
// C/D layout [m89]: l = lq*64+r*16+quad*4+rr, s = sq*64+j*16+lr
__global__ __launch_bounds__(256, 4) void conf_pass(
    const uint8_t* __restrict__ f0q, const uint8_t* __restrict__ f1q,
    float* __restrict__ rowSum, float* __restrict__ colSum,
    int* __restrict__ rowPart, int* __restrict__ colPart){
  __shared__ __align__(16) uint8_t Alds[128*128];
  __shared__ __align__(16) uint8_t Blds[128*128];
  float* rowS = (float*)Alds;            // [2][128] overlay (valid after MFMA)
  float* colS = (float*)(Alds + 1024);   // [2][128]
  int*   rb   = (int*)  (Alds + 2048);   // [2][128]
  int*   cb   = (int*)  (Alds + 3072);   // [2][128]
  // XCD-chunked swizzle: 2048 blocks, 8 XCDs, 256 contiguous tiles per XCD.
  int bl = (blockIdx.z*32 + blockIdx.y)*32 + blockIdx.x;
  int nb = (bl & 7)*256 + (bl >> 3);
  int st = nb & 31, lt = (nb >> 5) & 31, n = nb >> 10;
  int t = threadIdx.x;
  const int wv = t >> 6, lane = t & 63, lr = lane & 15, quad = lane >> 4;
  const int lq = wv >> 1, sq = wv & 1;
  const int swzr = (lr & 7) << 4;        // frag-read XOR (row&7 == lr&7)
  const uint8_t* A = f0q + (size_t)n*LL*CC + (size_t)(lt*128)*CC;
  const uint8_t* B = f1q + (size_t)n*LL*CC + (size_t)(st*128)*CC;
  f32x4 acc[4][4];
  #pragma unroll
  for (int r = 0; r < 4; r++)
    #pragma unroll
    for (int j = 0; j < 4; j++) acc[r][j] = (f32x4){0.f,0.f,0.f,0.f};

  auto compute = [&](){
    __builtin_amdgcn_s_setprio(1);
    #pragma unroll
    for (int kk = 0; kk < 4; kk++){
      int off = (kk*32 + quad*8) ^ swzr;
      i64f a[4], bf[4];
      #pragma unroll
      for (int r = 0; r < 4; r++)
        a[r] = *(const i64f*)(Alds + (lq*64 + r*16 + lr)*128 + off);
      #pragma unroll
      for (int j = 0; j < 4; j++)
        bf[j] = *(const i64f*)(Blds + (sq*64 + j*16 + lr)*128 + off);
      #pragma unroll
      for (int r = 0; r < 4; r++)
        #pragma unroll
        for (int j = 0; j < 4; j++)
          acc[r][j] = __builtin_amdgcn_mfma_f32_16x16x32_fp8_fp8(a[r], bf[j], acc[r][j], 0, 0, 0);
    }
    __builtin_amdgcn_s_setprio(0);
  };

  // ---- chunk 0: async global_load_lds, 16B/lane, pre-swizzled source ----
  {
    int rsub = lane >> 3, csub = lane & 7;
    int srcOff = ((csub ^ rsub) << 4);           // row&7 == rsub here
    #pragma unroll
    for (int m = 0; m < 4; m++){
      int row = m*32 + wv*8 + rsub;
      GLDS16(A + (size_t)row*CC + srcOff, Alds + m*4096 + wv*1024);
      GLDS16(B + (size_t)row*CC + srcOff, Blds + m*4096 + wv*1024);
    }
  }
  __builtin_amdgcn_sched_barrier(0);   // pin: 8 glds issue BEFORE prefetch loads
  // ---- chunk-1 prefetch into registers (stays in flight across compute 0) --
  uint2 pa[8], pb[8];
  #pragma unroll
  for (int m = 0; m < 8; m++){
    int f = m*256 + t, row = f >> 4, kg = f & 15;
    int so = (kg*8) ^ ((row & 7) << 4);
    pa[m] = *(const uint2*)(A + (size_t)row*CC + 128 + so);
    pb[m] = *(const uint2*)(B + (size_t)row*CC + 128 + so);
  }
  // wait ONLY the 8 oldest vmem ops (the glds) -> prefetch stays outstanding
  asm volatile("s_waitcnt vmcnt(16)" ::: "memory");
  __builtin_amdgcn_s_barrier();
  __builtin_amdgcn_sched_barrier(0);
  compute();          // chunk 0 (chunk-1 prefetch loads still in flight)
  __syncthreads();
  #pragma unroll
  for (int m = 0; m < 8; m++){
    int f = m*256 + t, row = f >> 4, kg = f & 15;
    *(uint2*)(Alds + row*128 + kg*8) = pa[m];
    *(uint2*)(Blds + row*128 + kg*8) = pb[m];
  }
  __syncthreads();
  compute();          // chunk 1

  // ---- epilogue: exp-sums + packed argmax keys -------------------------
  const int sbase = st*128 + sq*64 + lr;        // + j*16
  const int lbase = lt*128 + lq*64 + quad*4;    // + r*16 + rr
  float rv[16], cv[4] = {0.f,0.f,0.f,0.f};
  int rk[16], ck[4] = {IMIN,IMIN,IMIN,IMIN};
  #pragma unroll
  for (int i = 0; i < 16; i++){ rv[i] = 0.f; rk[i] = IMIN; }
  #pragma unroll
  for (int r = 0; r < 4; r++)
    #pragma unroll
    for (int j = 0; j < 4; j++)
      #pragma unroll
      for (int rr = 0; rr < 4; rr++){
        float a = acc[r][j][rr];
        float e = EXP2F(a * KEXP);
        rv[r*4+rr] += e;
        cv[j] += e;
        int iqs = ((int)(a * 2048.f)) << 12;
        rk[r*4+rr] = max(rk[r*4+rr], iqs + (sbase + j*16));
        ck[j]      = max(ck[j],      iqs + (lbase + r*16 + rr));
      }
  // ---- value-split butterfly over lr (16 lanes, 16 values) ----
  // After 4 steps, lane owns value V = bitrev4(lr): rv[0]/rk[0] fully reduced.
  {
    bool hi = (lr & 1) != 0;
    #pragma unroll
    for (int i = 0; i < 8; i++){
      float sf = hi ? rv[i] : rv[i+8], kf = hi ? rv[i+8] : rv[i];
      rv[i] = kf + __shfl_xor(sf, 1);
      int   si = hi ? rk[i] : rk[i+8]; int ki = hi ? rk[i+8] : rk[i];
      rk[i] = max(ki, __shfl_xor(si, 1));
    }
  }
  {
    bool hi = (lr & 2) != 0;
    #pragma unroll
    for (int i = 0; i < 4; i++){
      float sf = hi ? rv[i] : rv[i+4], kf = hi ? rv[i+4] : rv[i];
      rv[i] = kf + __shfl_xor(sf, 2);
      int   si = hi ? rk[i] : rk[i+4]; int ki = hi ? rk[i+4] : rk[i];
      rk[i] = max(ki, __shfl_xor(si, 2));
    }
  }
  {
    bool hi = (lr & 4) != 0;
    #pragma unroll
    for (int i = 0; i < 2; i++){
      float sf = hi ? rv[i] : rv[i+2], kf = hi ? rv[i+2] : rv[i];
      rv[i] = kf + __shfl_xor(sf, 4);
      int   si = hi ? rk[i] : rk[i+2]; int ki = hi ? rk[i+2] : rk[i];
      rk[i] = max(ki, __shfl_xor(si, 4));
    }
  }
  {
    bool hi = (lr & 8) != 0;
    float sf = hi ? rv[0] : rv[1], kf = hi ? rv[1] : rv[0];
    rv[0] = kf + __shfl_xor(sf, 8);
    int   si = hi ? rk[0] : rk[1]; int ki = hi ? rk[1] : rk[0];
    rk[0] = max(ki, __shfl_xor(si, 8));
  }
  // ---- same over quad (4 lane-groups, 4 values): lane-group owns J ----
  {
    bool hi = (lane & 16) != 0;
    #pragma unroll
    for (int i = 0; i < 2; i++){
      float sf = hi ? cv[i] : cv[i+2], kf = hi ? cv[i+2] : cv[i];
      cv[i] = kf + __shfl_xor(sf, 16);
      int   si = hi ? ck[i] : ck[i+2]; int ki = hi ? ck[i+2] : ck[i];
      ck[i] = max(ki, __shfl_xor(si, 16));
    }
  }
  {
    bool hi = (lane & 32) != 0;
    float sf = hi ? cv[0] : cv[1], kf = hi ? cv[1] : cv[0];
    cv[0] = kf + __shfl_xor(sf, 32);
    int   si = hi ? ck[0] : ck[1]; int ki = hi ? ck[1] : ck[0];
    ck[0] = max(ki, __shfl_xor(si, 32));
  }
  const int V = ((lr&1)<<3) | ((lr&2)<<1) | ((lr&4)>>1) | ((lr&8)>>3);
  const int J = ((quad&1)<<1) | (quad>>1);
  const int rowOwn = lq*64 + (V>>2)*16 + quad*4 + (V&3);
  const int colOwn = sq*64 + J*16 + lr;
  __syncthreads();   // all waves done reading tile LDS -> overlay is safe
  rowS[sq*128 + rowOwn] = rv[0];   // one store per lane, single writer/slot
  rb  [sq*128 + rowOwn] = rk[0];
  colS[lq*128 + colOwn] = cv[0];
  cb  [lq*128 + colOwn] = ck[0];
  __syncthreads();
  {
    int tt = t & 127;
    if (t < 128){
      unsafeAtomicAdd(&rowSum[(size_t)n*LL + lt*128 + tt], rowS[tt] + rowS[128 + tt]);
      atomicMax(&rowPart[(size_t)n*LL + lt*128 + tt], max(rb[tt], rb[128 + tt]));
    } else {
      unsafeAtomicAdd(&colSum[(size_t)n*LL + st*128 + tt], colS[tt] + colS[128 + tt]);
      atomicMax(&colPart[(size_t)n*LL + st*128 + tt], max(cb[tt], cb[128 + tt]));
    }
  }
}

// ---------------- on-the-fly fea for the rare mask hit ----------------
__device__ float fea_fly(const float* __restrict__ featn, int srow, int t){
  __shared__ float sred[9][4];
  __shared__ float ssem[9];
  int lane = t & 63, wv = t >> 6;
  int h = srow >> 6, xx = srow & 63;
  float fv = featn[(size_t)srow * CC + t];
  float uv[9];
  #pragma unroll
  for (int w = 0; w < 9; w++){
    int dy = w/3 - 1, dx = w%3 - 1;
    int y = h + dy, x = xx + dx;
    uv[w] = (y >= 0 && y < 64 && x >= 0 && x < 64) ? featn[(size_t)t * 4096 + y*64 + x] : 0.f;
  }
  __syncthreads();
  #pragma unroll
  for (int w = 0; w < 9; w++){
    float pvv = fv * uv[w];
    #pragma unroll
    for (int msk = 1; msk <= 32; msk <<= 1) pvv += __shfl_xor(pvv, msk);
    if (lane == 0) sred[w][wv] = pvv;
  }
  __syncthreads();
  if (t < 9) ssem[t] = (sred[t][0] + sred[t][1] + sred[t][2] + sred[t][3]) * (1.f/256.f);
  __syncthreads();
  float acc = 0.f;
  #pragma unroll
  for (int w = 0; w < 9; w++) acc += uv[w] * ssem[w];
  __syncthreads();
  return acc;
}

__device__ __forceinline__ float pool_window(const float* f, const float* s, int t){
  if (t < 160){
    int a = (t*8)/5, e = (t*8+12)/5;
    float sum = 0.f;
    for (int i = a; i < e; i++) sum += f[i];
    return sum / (float)(e - a);
  } else {
    int tt = t - 160;
    int a = (tt*8)/3, e = (tt*8+10)/3;
    float sum = 0.f;
    for (int i = a; i < e; i++) sum += s[i];
    return sum / (float)(e - a);
  }
}

// ---------------- fused tail: mutual-NN check + pool + LN -------------------
// R15: 4 rows per block; level-1/level-2 scalar gathers batched across rows.
__global__ __launch_bounds__(256) void tail(
    const float* __restrict__ feat0, const float* __restrict__ feat1,
    const float* __restrict__ rowSum, const float* __restrict__ colSum,
    const int* __restrict__ rowPart, const int* __restrict__ colPart,
    const float* __restrict__ lnw, const float* __restrict__ lnb,
    float* __restrict__ out){
  int l0 = blockIdx.x * 4, n = blockIdx.y, t = threadIdx.x;
  int lane = t & 63, wv = t >> 6;
  size_t base = (size_t)n * LL;
  float w = lnw[t], bsh = lnb[t];
  // ---- level-1 loads for all 4 rows (independent; issue together) ----
  float fv0[4], fv1[4], Rl[4], Cl[4];
  int rowK[4], colK[4];
  #pragma unroll
  for (int i = 0; i < 4; i++){
    fv0[i]  = feat0[(base + l0 + i)*CC + t];
    fv1[i]  = feat1[(base + l0 + i)*CC + t];
    rowK[i] = rowPart[base + l0 + i];
    colK[i] = colPart[base + l0 + i];
    Rl[i]   = rowSum[base + l0 + i];
    Cl[i]   = colSum[base + l0 + i];
  }
  // ---- level-2 gathers (depend only on level-1; issue together) ----
  int ssr[4], ssc[4], ck2[4], rk2[4];
  float Cssr[4], Rssc[4];
  #pragma unroll
  for (int i = 0; i < 4; i++){
    ssr[i] = rowK[i] & 4095;
    ssc[i] = colK[i] & 4095;
    Cssr[i] = colSum[base + ssr[i]];
    Rssc[i] = rowSum[base + ssc[i]];
    ck2[i]  = colPart[base + ssr[i]];
    rk2[i]  = rowPart[base + ssc[i]];
  }
  __shared__ float f0r[CC], f1r[CC], s0r[CC], s1r[CC];
  __shared__ float redA[2][4], redB[2][4];
  for (int i = 0; i < 4; i++){
    int l = l0 + i;
    float v0 = 0.f, v1 = 0.f;
    {
      float araw = (float)(rowK[i] >> 12) * (1.f/2048.f);
      float val = exp2f(araw * KEXP2) / (Rl[i] * Cssr[i]);   // conf'(l,ssr)
      if (val > 0.2f && (ck2[i] & 4095) == l)                // uniform branch
        v0 = fea_fly(feat1 + (size_t)n*LL*CC, ssr[i], t) * (1.f/4096.f);
    }
    {
      float araw = (float)(colK[i] >> 12) * (1.f/2048.f);
      float val = exp2f(araw * KEXP2) / (Cl[i] * Rssc[i]);   // conf'(ssc,l)
      if (val > 0.2f && (rk2[i] & 4095) == l)                // uniform branch
        v1 = fea_fly(feat0 + (size_t)n*LL*CC, ssc[i], t) * (1.f/4096.f);
    }
    // ---- pool + LN ----
    f0r[t] = fv0[i];
    f1r[t] = fv1[i];
    s0r[t] = v0;
    s1r[t] = v1;
    __syncthreads();
    float pA = pool_window(f0r, s0r, t);
    float pB = pool_window(f1r, s1r, t);
    float smA = pA, sqA = pA*pA, smB = pB, sqB = pB*pB;
    #pragma unroll
    for (int msk = 1; msk <= 32; msk <<= 1){
      smA += __shfl_xor(smA, msk);
      sqA += __shfl_xor(sqA, msk);
      smB += __shfl_xor(smB, msk);
      sqB += __shfl_xor(sqB, msk);
    }
    if (lane == 0){ redA[0][wv] = smA; redA[1][wv] = sqA; redB[0][wv] = smB; redB[1][wv] = sqB; }
    __syncthreads();
    float tsA = redA[0][0]+redA[0][1]+redA[0][2]+redA[0][3];
    float tqA = redA[1][0]+redA[1][1]+redA[1][2]+redA[1][3];
    float tsB = redB[0][0]+redB[0][1]+redB[0][2]+redB[0][3];
    float tqB = redB[1][0]+redB[1][1]+redB[1][2]+redB[1][3];
    float muA = tsA * (1.f/256.f), varA = tqA * (1.f/256.f) - muA*muA;
    float muB = tsB * (1.f/256.f), varB = tqB * (1.f/256.f) - muB*muB;
    out[((size_t)n*LL + l)*CC + t]       = (pA - muA) * rsqrtf(varA + 1e-5f) * w + bsh;
    out[((size_t)(2 + n)*LL + l)*CC + t] = (pB - muB) * rsqrtf(varB + 1e-5f) * w + bsh;
    __syncthreads();   // protect f0r..s1r / red* before next row's writes
  }
}

extern "C" void kernel_launch(void* const* d_in, const int* in_sizes, int n_in,
                              void* d_out, int out_size, void* d_ws, size_t ws_size,
                              hipStream_t stream){
  const float* feat0 = (const float*)d_in[0];
  const float* feat1 = (const float*)d_in[1];
  const float* lnw   = (const float*)d_in[2];
  const float* lnb   = (const float*)d_in[3];
  float* out = (float*)d_out;
  char* ws = (char*)d_ws;
  const size_t MB = 1024 * 1024;
  uint8_t* f0q = (uint8_t*)(ws + 0);        // 2 MB fp8
  uint8_t* f1q = (uint8_t*)(ws + 2*MB);     // 2 MB fp8
  float* rowSum  = (float*)(ws + 4*MB);            // [2][4096] = 32 KB
  float* colSum  = (float*)(ws + 4*MB + 32*1024);  // 32 KB
  int*   rowPart = (int*)  (ws + 4*MB + 64*1024);  // 32 KB
  int*   colPart = (int*)  (ws + 4*MB + 96*1024);  // 32 KB

  cast_fp8<<<2048, 256, 0, stream>>>(feat0, feat1, (uint32_t*)f0q, (uint32_t*)f1q,
                                     rowSum, colSum, rowPart, colPart);
  dim3 gconf(32, 32, NBATCH);
  conf_pass<<<gconf, 256, 0, stream>>>(f0q, f1q, rowSum, colSum, rowPart, colPart);
  dim3 gt(LL/4, NBATCH);
  tail<<<gt, 256, 0, stream>>>(feat0, feat1, rowSum, colSum, rowPart, colPart,
                               lnw, lnb, out);
}